// Round 1
// baseline (680.702 us; speedup 1.0000x reference)
//
#include <hip/hip_runtime.h>

// Problem constants (AttentionDeformModule)
#define BINS 5
#define PTS  2
constexpr int Bx = 2, Cc = 256, Hh = 100, Ww = 152;
constexpr int HW = Hh * Ww;          // 15200
constexpr float EPS_DIV = 1e-6f;
constexpr float GN_EPS  = 1e-5f;

// ---------------------------------------------------------------------------
// K1: ef = ef_w (512x256) @ x (256xHW) + ef_b, stored as efp[b][p][hw][c]
// Register-tiled fp32 GEMM: BM=64 (hw), BN=128 (out ch), BK=16, micro 4x8.
// ---------------------------------------------------------------------------
__global__ __launch_bounds__(256)
void k_ef_gemm(const float* __restrict__ x, const float* __restrict__ efw,
               const float* __restrict__ efb, float* __restrict__ efp)
{
    __shared__ float As[16][64];    // [k][m] slice of x
    __shared__ float Ws[16][128];   // [k][n] slice of ef_w
    const int t  = threadIdx.x;
    const int tx = t & 15, ty = t >> 4;
    const int m0 = blockIdx.x * 64;
    const int n0 = blockIdx.y * 128;
    const int b  = blockIdx.z;
    const float* xb = x + (size_t)b * Cc * HW;

    float acc[4][8];
    #pragma unroll
    for (int j = 0; j < 4; j++)
        #pragma unroll
        for (int i = 0; i < 8; i++) acc[j][i] = 0.f;

    const int kl = t >> 4, m4 = (t & 15) * 4;   // A-tile load coords
    const int nl = t >> 1, k8 = (t & 1) * 8;    // W-tile load coords

    for (int k0 = 0; k0 < 256; k0 += 16) {
        // x tile (16k x 64m), m-contiguous float4, zero-pad tail
        {
            int m = m0 + m4;
            int row = (k0 + kl) * HW;
            float4 v;
            if (m < HW) v = *(const float4*)(xb + row + m);
            else        v = float4{0.f, 0.f, 0.f, 0.f};
            *(float4*)&As[kl][m4] = v;
        }
        // ef_w tile (128n x 16k), load along k then transpose into LDS
        {
            const float* wp = efw + (size_t)(n0 + nl) * 256 + k0 + k8;
            float4 v0 = *(const float4*)(wp);
            float4 v1 = *(const float4*)(wp + 4);
            Ws[k8 + 0][nl] = v0.x; Ws[k8 + 1][nl] = v0.y;
            Ws[k8 + 2][nl] = v0.z; Ws[k8 + 3][nl] = v0.w;
            Ws[k8 + 4][nl] = v1.x; Ws[k8 + 5][nl] = v1.y;
            Ws[k8 + 6][nl] = v1.z; Ws[k8 + 7][nl] = v1.w;
        }
        __syncthreads();
        #pragma unroll
        for (int kk = 0; kk < 16; kk++) {
            float a[4], w[8];
            *(float4*)a       = *(const float4*)&As[kk][tx * 4];
            *(float4*)(w + 0) = *(const float4*)&Ws[kk][ty * 8 + 0];
            *(float4*)(w + 4) = *(const float4*)&Ws[kk][ty * 8 + 4];
            #pragma unroll
            for (int j = 0; j < 4; j++)
                #pragma unroll
                for (int i = 0; i < 8; i++) acc[j][i] += a[j] * w[i];
        }
        __syncthreads();
    }

    // epilogue: add bias, store to efp[b][p][m][c] (c-contiguous float4)
    const int nb = n0 + ty * 8;     // 8 consecutive output channels
    const int p  = nb >> 8;         // whole 8-run stays in one p (128 | 256)
    const int c0 = nb & 255;
    float bias[8];
    #pragma unroll
    for (int i = 0; i < 8; i++) bias[i] = efb[nb + i];
    float* outb = efp + (size_t)((b * PTS + p) * HW) * Cc;
    #pragma unroll
    for (int j = 0; j < 4; j++) {
        int m = m0 + tx * 4 + j;
        if (m < HW) {
            float4 v0 = {acc[j][0] + bias[0], acc[j][1] + bias[1],
                         acc[j][2] + bias[2], acc[j][3] + bias[3]};
            float4 v1 = {acc[j][4] + bias[4], acc[j][5] + bias[5],
                         acc[j][6] + bias[6], acc[j][7] + bias[7]};
            *(float4*)(outb + (size_t)m * Cc + c0)     = v0;
            *(float4*)(outb + (size_t)m * Cc + c0 + 4) = v1;
        }
    }
}

// ---------------------------------------------------------------------------
// K2: heat[b][p][hw] = exp( sum_d hm2_w[p][d] * relu( (hm1_w[p] @ efp)_d + hm1_b )
//                          + hm2_b[p] )
// Block tile: BM=64 pixels x BN=256 (all d) so the d-reduction fuses in-block.
// ---------------------------------------------------------------------------
__global__ __launch_bounds__(256)
void k_heat(const float* __restrict__ efp, const float* __restrict__ w1,
            const float* __restrict__ b1, const float* __restrict__ w2,
            const float* __restrict__ b2, float* __restrict__ heat)
{
    __shared__ float Ws[16][256];   // [k][d]
    __shared__ float Bs[16][64];    // [k][m]
    __shared__ float red[16][64];   // ty-partials for d-reduction
    const int t  = threadIdx.x;
    const int tx = t & 15, ty = t >> 4;
    const int m0 = blockIdx.x * 64;
    const int p  = blockIdx.y;
    const int b  = blockIdx.z;
    const float* ef  = efp + (size_t)((b * PTS + p) * HW) * Cc;
    const float* w1p = w1 + (size_t)p * Cc * Cc;

    float acc[4][16];
    #pragma unroll
    for (int j = 0; j < 4; j++)
        #pragma unroll
        for (int i = 0; i < 16; i++) acc[j][i] = 0.f;

    const int ml = t >> 2, k4 = (t & 3) * 4;

    for (int k0 = 0; k0 < 256; k0 += 16) {
        // hm1_w tile: thread t owns row d=t, 16 k via 4 float4, transpose-store
        {
            const float* wr = w1p + (size_t)t * 256 + k0;
            float4 v0 = *(const float4*)(wr + 0);
            float4 v1 = *(const float4*)(wr + 4);
            float4 v2 = *(const float4*)(wr + 8);
            float4 v3 = *(const float4*)(wr + 12);
            Ws[0][t] = v0.x;  Ws[1][t] = v0.y;  Ws[2][t] = v0.z;  Ws[3][t] = v0.w;
            Ws[4][t] = v1.x;  Ws[5][t] = v1.y;  Ws[6][t] = v1.z;  Ws[7][t] = v1.w;
            Ws[8][t] = v2.x;  Ws[9][t] = v2.y;  Ws[10][t] = v2.z; Ws[11][t] = v2.w;
            Ws[12][t] = v3.x; Ws[13][t] = v3.y; Ws[14][t] = v3.z; Ws[15][t] = v3.w;
        }
        // efp tile: (16k x 64m); efp is c-contiguous, load along k + transpose
        {
            int m = m0 + ml; if (m > HW - 1) m = HW - 1;   // clamp (guarded later)
            float4 v = *(const float4*)(ef + (size_t)m * Cc + k0 + k4);
            Bs[k4 + 0][ml] = v.x; Bs[k4 + 1][ml] = v.y;
            Bs[k4 + 2][ml] = v.z; Bs[k4 + 3][ml] = v.w;
        }
        __syncthreads();
        #pragma unroll
        for (int kk = 0; kk < 16; kk++) {
            float a[4], wv[16];
            *(float4*)a         = *(const float4*)&Bs[kk][tx * 4];
            *(float4*)(wv + 0)  = *(const float4*)&Ws[kk][ty * 16 + 0];
            *(float4*)(wv + 4)  = *(const float4*)&Ws[kk][ty * 16 + 4];
            *(float4*)(wv + 8)  = *(const float4*)&Ws[kk][ty * 16 + 8];
            *(float4*)(wv + 12) = *(const float4*)&Ws[kk][ty * 16 + 12];
            #pragma unroll
            for (int i = 0; i < 16; i++)
                #pragma unroll
                for (int j = 0; j < 4; j++) acc[j][i] += a[j] * wv[i];
        }
        __syncthreads();
    }

    // epilogue: bias + relu + weight by hm2_w, reduce over d
    const int d0 = ty * 16;
    float contrib[4] = {0.f, 0.f, 0.f, 0.f};
    #pragma unroll
    for (int i = 0; i < 16; i++) {
        float bb = b1[p * 256 + d0 + i];
        float ww = w2[p * 256 + d0 + i];
        #pragma unroll
        for (int j = 0; j < 4; j++) {
            float h = acc[j][i] + bb;
            h = h > 0.f ? h : 0.f;
            contrib[j] += ww * h;
        }
    }
    *(float4*)&red[ty][tx * 4] = *(float4*)contrib;
    __syncthreads();
    if (t < 64) {
        float s = 0.f;
        #pragma unroll
        for (int u = 0; u < 16; u++) s += red[u][t];
        int m = m0 + t;
        if (m < HW)
            heat[(size_t)(b * PTS + p) * HW + m] = expf(s + b2[p]);
    }
}

// ---------------------------------------------------------------------------
// K3: deformable sampling.
// outs[b][hw][p*256+c] = ( sum_{k,corner} w*valid*heat[src] * efp[src][c] )
//                        / ( sum w*valid*heat[src] + eps )
// 32-pixel tiles; phase1 builds (weight*heat/denominator, index) lists in LDS,
// phase2: lane=channel coalesced gather sweep.
// ---------------------------------------------------------------------------
__global__ __launch_bounds__(256)
void k_sample(const float* __restrict__ efp, const float* __restrict__ heat,
              const float* __restrict__ offs, float* __restrict__ outs)
{
    __shared__ float s_wh[32][20];
    __shared__ int   s_idx[32][20];
    const int t  = threadIdx.x;
    const int m0 = blockIdx.x * 32;     // 475*32 == 15200 exactly
    const int p  = blockIdx.y;
    const int b  = blockIdx.z;
    const float* heat_bp = heat + (size_t)(b * PTS + p) * HW;

    if (t < 32 * BINS) {
        int j = t / BINS, k = t % BINS;
        int hw = m0 + j;
        int hh = hw / Ww, ww = hw % Ww;
        int chy = (p * BINS + k) * 2;
        float oy = offs[((size_t)b * (PTS * BINS * 2) + chy)     * HW + hw];
        float ox = offs[((size_t)b * (PTS * BINS * 2) + chy + 1) * HW + hw];
        float ysf = (float)hh + oy;
        float xsf = (float)ww + ox;
        float y0 = floorf(ysf), x0 = floorf(xsf);
        #pragma unroll
        for (int dy = 0; dy < 2; dy++)
            #pragma unroll
            for (int dx = 0; dx < 2; dx++) {
                float yi = y0 + dy, xi = x0 + dx;
                float wgt = (1.f - fabsf(ysf - yi)) * (1.f - fabsf(xsf - xi));
                bool valid = (yi >= 0.f) && (yi <= (float)(Hh - 1)) &&
                             (xi >= 0.f) && (xi <= (float)(Ww - 1));
                int yc = (int)yi; yc = yc < 0 ? 0 : (yc > Hh - 1 ? Hh - 1 : yc);
                int xc = (int)xi; xc = xc < 0 ? 0 : (xc > Ww - 1 ? Ww - 1 : xc);
                int idx = yc * Ww + xc;
                float wh = valid ? wgt * heat_bp[idx] : 0.f;
                s_wh[j][k * 4 + dy * 2 + dx]  = wh;
                s_idx[j][k * 4 + dy * 2 + dx] = idx;
            }
    }
    __syncthreads();
    if (t < 32) {
        float s = 0.f;
        #pragma unroll
        for (int u = 0; u < 20; u++) s += s_wh[t][u];
        float inv = 1.f / (s + EPS_DIV);
        #pragma unroll
        for (int u = 0; u < 20; u++) s_wh[t][u] *= inv;
    }
    __syncthreads();

    // phase 2: lane t = channel c
    const float* ef = efp + (size_t)((b * PTS + p) * HW) * Cc + t;
    float* ob = outs + ((size_t)(b * HW + m0)) * (PTS * Cc) + p * Cc + t;
    for (int j = 0; j < 32; j++) {
        float a = 0.f;
        #pragma unroll
        for (int u = 0; u < 20; u++)
            a += s_wh[j][u] * ef[(size_t)s_idx[j][u] * Cc];
        ob[(size_t)j * (PTS * Cc)] = a;
    }
}

// ---------------------------------------------------------------------------
// K4: merged = merge_w (256x512) @ outs^T (512xHW) + merge_b  -> d_out[b][c][hw]
// ---------------------------------------------------------------------------
__global__ __launch_bounds__(256)
void k_merge(const float* __restrict__ outs, const float* __restrict__ mw,
             const float* __restrict__ mb, float* __restrict__ out)
{
    __shared__ float Bs[16][64];    // [k][m]
    __shared__ float Ws[16][128];   // [k][n]
    const int t  = threadIdx.x;
    const int tx = t & 15, ty = t >> 4;
    const int m0 = blockIdx.x * 64;
    const int n0 = blockIdx.y * 128;
    const int b  = blockIdx.z;
    const float* ob = outs + (size_t)b * HW * (PTS * Cc);

    float acc[4][8];
    #pragma unroll
    for (int j = 0; j < 4; j++)
        #pragma unroll
        for (int i = 0; i < 8; i++) acc[j][i] = 0.f;

    const int ml = t >> 2, k4 = (t & 3) * 4;
    const int nl = t >> 1, k8 = (t & 1) * 8;

    for (int k0 = 0; k0 < 512; k0 += 16) {
        {
            int m = m0 + ml; if (m > HW - 1) m = HW - 1;
            float4 v = *(const float4*)(ob + (size_t)m * (PTS * Cc) + k0 + k4);
            Bs[k4 + 0][ml] = v.x; Bs[k4 + 1][ml] = v.y;
            Bs[k4 + 2][ml] = v.z; Bs[k4 + 3][ml] = v.w;
        }
        {
            const float* wp = mw + (size_t)(n0 + nl) * 512 + k0 + k8;
            float4 v0 = *(const float4*)(wp);
            float4 v1 = *(const float4*)(wp + 4);
            Ws[k8 + 0][nl] = v0.x; Ws[k8 + 1][nl] = v0.y;
            Ws[k8 + 2][nl] = v0.z; Ws[k8 + 3][nl] = v0.w;
            Ws[k8 + 4][nl] = v1.x; Ws[k8 + 5][nl] = v1.y;
            Ws[k8 + 6][nl] = v1.z; Ws[k8 + 7][nl] = v1.w;
        }
        __syncthreads();
        #pragma unroll
        for (int kk = 0; kk < 16; kk++) {
            float a[4], w[8];
            *(float4*)a       = *(const float4*)&Bs[kk][tx * 4];
            *(float4*)(w + 0) = *(const float4*)&Ws[kk][ty * 8 + 0];
            *(float4*)(w + 4) = *(const float4*)&Ws[kk][ty * 8 + 4];
            #pragma unroll
            for (int j = 0; j < 4; j++)
                #pragma unroll
                for (int i = 0; i < 8; i++) acc[j][i] += a[j] * w[i];
        }
        __syncthreads();
    }

    const int nb = n0 + ty * 8;
    const int m  = m0 + tx * 4;
    if (m < HW) {
        #pragma unroll
        for (int i = 0; i < 8; i++) {
            int nn = nb + i;
            float bias = mb[nn];
            float4 v = {acc[0][i] + bias, acc[1][i] + bias,
                        acc[2][i] + bias, acc[3][i] + bias};
            *(float4*)(out + ((size_t)b * Cc + nn) * HW + m) = v;
        }
    }
}

// ---------------------------------------------------------------------------
// K5: GroupNorm stats per (b, group): mean & inv_std over 8 channels * HW
// ---------------------------------------------------------------------------
__global__ __launch_bounds__(256)
void k_gnstats(const float* __restrict__ mg, float* __restrict__ stats)
{
    const int g = blockIdx.x, b = blockIdx.y;
    const float* base = mg + ((size_t)b * Cc + g * 8) * HW;
    const int n = 8 * HW;
    float s = 0.f, q = 0.f;
    for (int i = threadIdx.x; i < n; i += 256) {
        float v = base[i];
        s += v; q += v * v;
    }
    #pragma unroll
    for (int off = 32; off > 0; off >>= 1) {
        s += __shfl_down(s, off);
        q += __shfl_down(q, off);
    }
    __shared__ float rs[4], rq[4];
    int wid = threadIdx.x >> 6, lane = threadIdx.x & 63;
    if (lane == 0) { rs[wid] = s; rq[wid] = q; }
    __syncthreads();
    if (threadIdx.x == 0) {
        float S = rs[0] + rs[1] + rs[2] + rs[3];
        float Q = rq[0] + rq[1] + rq[2] + rq[3];
        float mean = S / (float)n;
        float var  = Q / (float)n - mean * mean;
        stats[(b * 32 + g) * 2 + 0] = mean;
        stats[(b * 32 + g) * 2 + 1] = rsqrtf(var + GN_EPS);
    }
}

// ---------------------------------------------------------------------------
// K6: apply GN scale/shift + ReLU in place (float4 grid-stride, exact grid)
// ---------------------------------------------------------------------------
__global__ __launch_bounds__(256)
void k_gnapply(float* __restrict__ out, const float* __restrict__ stats,
               const float* __restrict__ gg, const float* __restrict__ gb)
{
    const int i4 = blockIdx.x * 256 + threadIdx.x;
    const int total4 = Bx * Cc * HW / 4;
    if (i4 >= total4) return;
    const int i = i4 * 4;
    const int CHW = Cc * HW;
    const int b = i / CHW;
    const int r = i - b * CHW;
    const int c = r / HW;
    const int g = c >> 3;
    float mean = stats[(b * 32 + g) * 2 + 0];
    float istd = stats[(b * 32 + g) * 2 + 1];
    float sc = istd * gg[c];
    float sh = gb[c] - mean * sc;
    float4 v = *(float4*)(out + i);
    v.x = fmaxf(v.x * sc + sh, 0.f);
    v.y = fmaxf(v.y * sc + sh, 0.f);
    v.z = fmaxf(v.z * sc + sh, 0.f);
    v.w = fmaxf(v.w * sc + sh, 0.f);
    *(float4*)(out + i) = v;
}

// ---------------------------------------------------------------------------
extern "C" void kernel_launch(void* const* d_in, const int* in_sizes, int n_in,
                              void* d_out, int out_size, void* d_ws, size_t ws_size,
                              hipStream_t stream)
{
    const float* x    = (const float*)d_in[0];
    const float* offs = (const float*)d_in[1];
    const float* efw  = (const float*)d_in[2];
    const float* efb  = (const float*)d_in[3];
    const float* w1   = (const float*)d_in[4];
    const float* b1   = (const float*)d_in[5];
    const float* w2   = (const float*)d_in[6];
    const float* b2   = (const float*)d_in[7];
    const float* mw   = (const float*)d_in[8];
    const float* mb   = (const float*)d_in[9];
    const float* gg   = (const float*)d_in[10];
    const float* gb   = (const float*)d_in[11];
    float* out = (float*)d_out;

    float* ws   = (float*)d_ws;
    float* efp  = ws;                                        // B*P*HW*C floats
    float* heat = efp  + (size_t)Bx * PTS * HW * Cc;         // B*P*HW
    float* outs = heat + (size_t)Bx * PTS * HW;              // B*HW*P*C
    float* stat = outs + (size_t)Bx * HW * PTS * Cc;         // B*32*2

    dim3 blk(256);
    k_ef_gemm<<<dim3((HW + 63) / 64, 4, Bx),   blk, 0, stream>>>(x, efw, efb, efp);
    k_heat   <<<dim3((HW + 63) / 64, PTS, Bx), blk, 0, stream>>>(efp, w1, b1, w2, b2, heat);
    k_sample <<<dim3(HW / 32, PTS, Bx),        blk, 0, stream>>>(efp, heat, offs, outs);
    k_merge  <<<dim3((HW + 63) / 64, 2, Bx),   blk, 0, stream>>>(outs, mw, mb, out);
    k_gnstats<<<dim3(32, Bx),                  blk, 0, stream>>>(out, stat);
    k_gnapply<<<dim3(Bx * Cc * HW / 4 / 256),  blk, 0, stream>>>(out, stat, gg, gb);
}

// Round 2
// 396.455 us; speedup vs baseline: 1.7170x; 1.7170x over previous
//
#include <hip/hip_runtime.h>

#define BINS 5
#define PTS  2
constexpr int Bx = 2, Cc = 256, Hh = 100, Ww = 152;
constexpr int HW = Hh * Ww;          // 15200
constexpr float EPS_DIV = 1e-6f;
constexpr float GN_EPS  = 1e-5f;

typedef __attribute__((ext_vector_type(8))) short bfrag;   // 8 bf16 (4 VGPRs)
typedef __attribute__((ext_vector_type(4))) float f32x4;   // MFMA C/D

__device__ __forceinline__ ushort f2bf(float f) {
    union { float f; unsigned u; } v; v.f = f;
    unsigned r = v.u + 0x7fffu + ((v.u >> 16) & 1u);
    return (ushort)(r >> 16);
}
__device__ __forceinline__ float bf2f(ushort h) {
    union { unsigned u; float f; } v; v.u = ((unsigned)h) << 16;
    return v.f;
}

// ---------------------------------------------------------------------------
// K0: convert ef_w (512x256), hm1_w (2x256x256), merge_w (256x512) to bf16.
// Each array is exactly 131072 = 2^17 elements.
// ---------------------------------------------------------------------------
__global__ __launch_bounds__(256)
void k_wconv(const float* __restrict__ efw, const float* __restrict__ w1,
             const float* __restrict__ mw, ushort* __restrict__ wb)
{
    int gid = blockIdx.x * 256 + threadIdx.x;
    int e = gid * 4;                       // 393216 total elements
    int arr = e >> 17, off = e & 131071;
    const float* src = arr == 0 ? efw : (arr == 1 ? w1 : mw);
    float4 v = *(const float4*)(src + off);
    ushort4 o = { f2bf(v.x), f2bf(v.y), f2bf(v.z), f2bf(v.w) };
    *(ushort4*)(wb + e) = o;
}

// ---------------------------------------------------------------------------
// K1: efp[b][p][pix][c] (bf16) = ef_w @ x + ef_b.
// MFMA 16x16x32 bf16. A = weights [n][k] (row=channel), B = x [k][pix]
// transposed+converted into LDS [pix][k]. Tile: 128 ch x 64 pix, BK=64.
// ---------------------------------------------------------------------------
__global__ __launch_bounds__(256)
void k_ef(const float* __restrict__ x, const ushort* __restrict__ wbe,
          const float* __restrict__ efb, ushort* __restrict__ efp)
{
    __shared__ ushort As[128 * 72];     // [n][k] pad 72
    __shared__ ushort Bs[64 * 72];      // [pix][k]
    const int t = threadIdx.x;
    const int wv = t >> 6, ln = t & 63;
    const int quad = ln >> 4, l16 = ln & 15;
    const int pix0 = blockIdx.x * 64;
    const int n0 = blockIdx.y * 128;
    const int b = blockIdx.z;
    const float* xb = x + (size_t)b * Cc * HW;

    f32x4 acc[2][4];
    #pragma unroll
    for (int i = 0; i < 2; i++)
        #pragma unroll
        for (int j = 0; j < 4; j++) acc[i][j] = (f32x4){0.f, 0.f, 0.f, 0.f};

    const int arow = t >> 3, acol = (t & 7) * 8;
    const int bpix = t & 63, bkg = (t >> 6) * 8;
    int pp = pix0 + bpix; if (pp > HW - 1) pp = HW - 1;

    for (int k0 = 0; k0 < 256; k0 += 64) {
        #pragma unroll
        for (int r = 0; r < 4; r++) {
            int row = arow + r * 32;
            *(uint4*)&As[row * 72 + acol] =
                *(const uint4*)&wbe[(size_t)(n0 + row) * 256 + k0 + acol];
        }
        #pragma unroll
        for (int r = 0; r < 2; r++) {
            int kc = bkg + r * 32;
            union { ushort s[8]; uint4 v; } tmp;
            #pragma unroll
            for (int j = 0; j < 8; j++)
                tmp.s[j] = f2bf(xb[(size_t)(k0 + kc + j) * HW + pp]);
            *(uint4*)&Bs[bpix * 72 + kc] = tmp.v;
        }
        __syncthreads();
        #pragma unroll
        for (int kk = 0; kk < 64; kk += 32) {
            bfrag af[2], bfr[4];
            #pragma unroll
            for (int dt = 0; dt < 2; dt++)
                af[dt] = *(const bfrag*)&As[(wv * 32 + dt * 16 + l16) * 72 + kk + quad * 8];
            #pragma unroll
            for (int pt = 0; pt < 4; pt++)
                bfr[pt] = *(const bfrag*)&Bs[(pt * 16 + l16) * 72 + kk + quad * 8];
            #pragma unroll
            for (int dt = 0; dt < 2; dt++)
                #pragma unroll
                for (int pt = 0; pt < 4; pt++)
                    acc[dt][pt] = __builtin_amdgcn_mfma_f32_16x16x32_bf16(
                        af[dt], bfr[pt], acc[dt][pt], 0, 0, 0);
        }
        __syncthreads();
    }

    // epilogue: bias, bf16, transpose via LDS (reuse As: [pix][ch] pad 136)
    float bias[2][4];
    #pragma unroll
    for (int dt = 0; dt < 2; dt++)
        #pragma unroll
        for (int r = 0; r < 4; r++)
            bias[dt][r] = efb[n0 + wv * 32 + dt * 16 + quad * 4 + r];
    #pragma unroll
    for (int dt = 0; dt < 2; dt++)
        #pragma unroll
        for (int pt = 0; pt < 4; pt++) {
            int pix = pt * 16 + l16;
            int ch = wv * 32 + dt * 16 + quad * 4;
            ushort4 o = { f2bf(acc[dt][pt][0] + bias[dt][0]),
                          f2bf(acc[dt][pt][1] + bias[dt][1]),
                          f2bf(acc[dt][pt][2] + bias[dt][2]),
                          f2bf(acc[dt][pt][3] + bias[dt][3]) };
            *(ushort4*)&As[pix * 136 + ch] = o;
        }
    __syncthreads();
    const int p = n0 >> 8, cbase = n0 & 255;
    ushort* outb = efp + (size_t)((b * PTS + p) * HW) * Cc;
    #pragma unroll
    for (int r = 0; r < 4; r++) {
        int pix = (t >> 4) + r * 16;
        int ch8 = (t & 15) * 8;
        if (pix0 + pix < HW)
            *(uint4*)&outb[(size_t)(pix0 + pix) * Cc + cbase + ch8] =
                *(const uint4*)&As[pix * 136 + ch8];
    }
}

// ---------------------------------------------------------------------------
// K2: heat[b][p][pix] = exp(sum_d w2[d]*relu(D[d][pix]+b1[d]) + b2)
// D = hm1_w[p] @ efp[b][p].  Tile: 256 ch (all) x 64 pix, BK=64.
// ---------------------------------------------------------------------------
__global__ __launch_bounds__(256)
void k_heat(const ushort* __restrict__ efp, const ushort* __restrict__ wb1,
            const float* __restrict__ b1, const float* __restrict__ w2,
            const float* __restrict__ b2, float* __restrict__ heat)
{
    __shared__ ushort As[256 * 72];
    __shared__ ushort Bs[64 * 72];
    __shared__ float red[4][64];
    const int t = threadIdx.x;
    const int wv = t >> 6, ln = t & 63;
    const int quad = ln >> 4, l16 = ln & 15;
    const int pix0 = blockIdx.x * 64;
    const int p = blockIdx.y;
    const int b = blockIdx.z;
    const ushort* efb_ = efp + (size_t)((b * PTS + p) * HW) * Cc;
    const ushort* w1p = wb1 + (size_t)p * Cc * Cc;

    f32x4 acc[4][4];
    #pragma unroll
    for (int i = 0; i < 4; i++)
        #pragma unroll
        for (int j = 0; j < 4; j++) acc[i][j] = (f32x4){0.f, 0.f, 0.f, 0.f};

    const int srow = t >> 3, scol = (t & 7) * 8;

    for (int k0 = 0; k0 < 256; k0 += 64) {
        #pragma unroll
        for (int r = 0; r < 8; r++) {
            int row = srow + r * 32;
            *(uint4*)&As[row * 72 + scol] =
                *(const uint4*)&w1p[(size_t)row * 256 + k0 + scol];
        }
        #pragma unroll
        for (int r = 0; r < 2; r++) {
            int row = srow + r * 32;
            int pp = pix0 + row; if (pp > HW - 1) pp = HW - 1;
            *(uint4*)&Bs[row * 72 + scol] =
                *(const uint4*)&efb_[(size_t)pp * Cc + k0 + scol];
        }
        __syncthreads();
        #pragma unroll
        for (int kk = 0; kk < 64; kk += 32) {
            bfrag af[4], bfr[4];
            #pragma unroll
            for (int dt = 0; dt < 4; dt++)
                af[dt] = *(const bfrag*)&As[(wv * 64 + dt * 16 + l16) * 72 + kk + quad * 8];
            #pragma unroll
            for (int pt = 0; pt < 4; pt++)
                bfr[pt] = *(const bfrag*)&Bs[(pt * 16 + l16) * 72 + kk + quad * 8];
            #pragma unroll
            for (int dt = 0; dt < 4; dt++)
                #pragma unroll
                for (int pt = 0; pt < 4; pt++)
                    acc[dt][pt] = __builtin_amdgcn_mfma_f32_16x16x32_bf16(
                        af[dt], bfr[pt], acc[dt][pt], 0, 0, 0);
        }
        __syncthreads();
    }

    const float* b1p = b1 + p * 256;
    const float* w2p = w2 + p * 256;
    float s[4] = {0.f, 0.f, 0.f, 0.f};
    #pragma unroll
    for (int dt = 0; dt < 4; dt++) {
        int chb = wv * 64 + dt * 16 + quad * 4;
        float bb[4], ww[4];
        #pragma unroll
        for (int r = 0; r < 4; r++) { bb[r] = b1p[chb + r]; ww[r] = w2p[chb + r]; }
        #pragma unroll
        for (int pt = 0; pt < 4; pt++)
            #pragma unroll
            for (int r = 0; r < 4; r++) {
                float h = acc[dt][pt][r] + bb[r];
                h = h > 0.f ? h : 0.f;
                s[pt] += ww[r] * h;
            }
    }
    #pragma unroll
    for (int pt = 0; pt < 4; pt++) {
        s[pt] += __shfl_xor(s[pt], 16);
        s[pt] += __shfl_xor(s[pt], 32);
    }
    if (ln < 16) {
        #pragma unroll
        for (int pt = 0; pt < 4; pt++) red[wv][pt * 16 + ln] = s[pt];
    }
    __syncthreads();
    if (t < 64) {
        float v = red[0][t] + red[1][t] + red[2][t] + red[3][t] + b2[p];
        int m = pix0 + t;
        if (m < HW) heat[(size_t)(b * PTS + p) * HW + m] = expf(v);
    }
}

// ---------------------------------------------------------------------------
// K3: deformable sampling (bf16 gathers, XCD-swizzled blocks)
// ---------------------------------------------------------------------------
__global__ __launch_bounds__(256)
void k_sample(const ushort* __restrict__ efp, const float* __restrict__ heat,
              const float* __restrict__ offs, ushort* __restrict__ outs)
{
    __shared__ float s_wh[32][20];
    __shared__ int   s_idx[32][20];
    const int t = threadIdx.x;
    const int bid = blockIdx.x;
    const int nx = (bid & 7) * 60 + (bid >> 3);   // XCD-contiguous bands
    if (nx >= 475) return;
    const int m0 = nx * 32;
    const int p = blockIdx.y;
    const int b = blockIdx.z;
    const float* heat_bp = heat + (size_t)(b * PTS + p) * HW;

    if (t < 32 * BINS) {
        int j = t / BINS, k = t % BINS;
        int hw = m0 + j;
        int hh = hw / Ww, ww = hw % Ww;
        int chy = (p * BINS + k) * 2;
        float oy = offs[((size_t)b * (PTS * BINS * 2) + chy)     * HW + hw];
        float ox = offs[((size_t)b * (PTS * BINS * 2) + chy + 1) * HW + hw];
        float ysf = (float)hh + oy;
        float xsf = (float)ww + ox;
        float y0 = floorf(ysf), x0 = floorf(xsf);
        #pragma unroll
        for (int dy = 0; dy < 2; dy++)
            #pragma unroll
            for (int dx = 0; dx < 2; dx++) {
                float yi = y0 + dy, xi = x0 + dx;
                float wgt = (1.f - fabsf(ysf - yi)) * (1.f - fabsf(xsf - xi));
                bool valid = (yi >= 0.f) && (yi <= (float)(Hh - 1)) &&
                             (xi >= 0.f) && (xi <= (float)(Ww - 1));
                int yc = (int)yi; yc = yc < 0 ? 0 : (yc > Hh - 1 ? Hh - 1 : yc);
                int xc = (int)xi; xc = xc < 0 ? 0 : (xc > Ww - 1 ? Ww - 1 : xc);
                int idx = yc * Ww + xc;
                float wh = valid ? wgt * heat_bp[idx] : 0.f;
                s_wh[j][k * 4 + dy * 2 + dx]  = wh;
                s_idx[j][k * 4 + dy * 2 + dx] = idx;
            }
    }
    __syncthreads();
    if (t < 32) {
        float s = 0.f;
        #pragma unroll
        for (int u = 0; u < 20; u++) s += s_wh[t][u];
        float inv = 1.f / (s + EPS_DIV);
        #pragma unroll
        for (int u = 0; u < 20; u++) s_wh[t][u] *= inv;
    }
    __syncthreads();

    const ushort* ef = efp + (size_t)((b * PTS + p) * HW) * Cc + t;
    ushort* ob = outs + ((size_t)(b * HW + m0)) * (PTS * Cc) + p * Cc + t;
    for (int j = 0; j < 32; j++) {
        float a = 0.f;
        #pragma unroll
        for (int u = 0; u < 20; u++)
            a += s_wh[j][u] * bf2f(ef[(size_t)s_idx[j][u] * Cc]);
        ob[(size_t)j * (PTS * Cc)] = f2bf(a);
    }
}

// ---------------------------------------------------------------------------
// K4: out[b][c][pix] (fp32) = merge_w @ outs + merge_b.
// Tile: 128 ch x 64 pix, BK=64, K=512.  B = outs [pix][512] direct.
// ---------------------------------------------------------------------------
__global__ __launch_bounds__(256)
void k_merge(const ushort* __restrict__ outs, const ushort* __restrict__ wbm,
             const float* __restrict__ mb, float* __restrict__ out)
{
    __shared__ ushort As[128 * 72];
    __shared__ ushort Bs[64 * 72];
    const int t = threadIdx.x;
    const int wv = t >> 6, ln = t & 63;
    const int quad = ln >> 4, l16 = ln & 15;
    const int pix0 = blockIdx.x * 64;
    const int n0 = blockIdx.y * 128;
    const int b = blockIdx.z;
    const ushort* ob = outs + (size_t)b * HW * (PTS * Cc);

    f32x4 acc[2][4];
    #pragma unroll
    for (int i = 0; i < 2; i++)
        #pragma unroll
        for (int j = 0; j < 4; j++) acc[i][j] = (f32x4){0.f, 0.f, 0.f, 0.f};

    const int srow = t >> 3, scol = (t & 7) * 8;

    for (int k0 = 0; k0 < 512; k0 += 64) {
        #pragma unroll
        for (int r = 0; r < 4; r++) {
            int row = srow + r * 32;
            *(uint4*)&As[row * 72 + scol] =
                *(const uint4*)&wbm[(size_t)(n0 + row) * 512 + k0 + scol];
        }
        #pragma unroll
        for (int r = 0; r < 2; r++) {
            int row = srow + r * 32;
            int pp = pix0 + row; if (pp > HW - 1) pp = HW - 1;
            *(uint4*)&Bs[row * 72 + scol] =
                *(const uint4*)&ob[(size_t)pp * (PTS * Cc) + k0 + scol];
        }
        __syncthreads();
        #pragma unroll
        for (int kk = 0; kk < 64; kk += 32) {
            bfrag af[2], bfr[4];
            #pragma unroll
            for (int dt = 0; dt < 2; dt++)
                af[dt] = *(const bfrag*)&As[(wv * 32 + dt * 16 + l16) * 72 + kk + quad * 8];
            #pragma unroll
            for (int pt = 0; pt < 4; pt++)
                bfr[pt] = *(const bfrag*)&Bs[(pt * 16 + l16) * 72 + kk + quad * 8];
            #pragma unroll
            for (int dt = 0; dt < 2; dt++)
                #pragma unroll
                for (int pt = 0; pt < 4; pt++)
                    acc[dt][pt] = __builtin_amdgcn_mfma_f32_16x16x32_bf16(
                        af[dt], bfr[pt], acc[dt][pt], 0, 0, 0);
        }
        __syncthreads();
    }

    float bias[2][4];
    #pragma unroll
    for (int dt = 0; dt < 2; dt++)
        #pragma unroll
        for (int r = 0; r < 4; r++)
            bias[dt][r] = mb[n0 + wv * 32 + dt * 16 + quad * 4 + r];
    #pragma unroll
    for (int dt = 0; dt < 2; dt++)
        #pragma unroll
        for (int pt = 0; pt < 4; pt++) {
            int ch = n0 + wv * 32 + dt * 16 + quad * 4;
            int pix = pix0 + pt * 16 + l16;
            if (pix < HW) {
                #pragma unroll
                for (int r = 0; r < 4; r++)
                    out[((size_t)b * Cc + ch + r) * HW + pix] =
                        acc[dt][pt][r] + bias[dt][r];
            }
        }
}

// ---------------------------------------------------------------------------
// K5/K6: GroupNorm stats + apply (unchanged)
// ---------------------------------------------------------------------------
__global__ __launch_bounds__(256)
void k_gnstats(const float* __restrict__ mg, float* __restrict__ stats)
{
    const int g = blockIdx.x, b = blockIdx.y;
    const float* base = mg + ((size_t)b * Cc + g * 8) * HW;
    const int n = 8 * HW;
    float s = 0.f, q = 0.f;
    for (int i = threadIdx.x; i < n; i += 256) {
        float v = base[i];
        s += v; q += v * v;
    }
    #pragma unroll
    for (int off = 32; off > 0; off >>= 1) {
        s += __shfl_down(s, off);
        q += __shfl_down(q, off);
    }
    __shared__ float rs[4], rq[4];
    int wid = threadIdx.x >> 6, lane = threadIdx.x & 63;
    if (lane == 0) { rs[wid] = s; rq[wid] = q; }
    __syncthreads();
    if (threadIdx.x == 0) {
        float S = rs[0] + rs[1] + rs[2] + rs[3];
        float Q = rq[0] + rq[1] + rq[2] + rq[3];
        float mean = S / (float)n;
        float var  = Q / (float)n - mean * mean;
        stats[(b * 32 + g) * 2 + 0] = mean;
        stats[(b * 32 + g) * 2 + 1] = rsqrtf(var + GN_EPS);
    }
}

__global__ __launch_bounds__(256)
void k_gnapply(float* __restrict__ out, const float* __restrict__ stats,
               const float* __restrict__ gg, const float* __restrict__ gb)
{
    const int i4 = blockIdx.x * 256 + threadIdx.x;
    const int total4 = Bx * Cc * HW / 4;
    if (i4 >= total4) return;
    const int i = i4 * 4;
    const int CHW = Cc * HW;
    const int b = i / CHW;
    const int r = i - b * CHW;
    const int c = r / HW;
    const int g = c >> 3;
    float mean = stats[(b * 32 + g) * 2 + 0];
    float istd = stats[(b * 32 + g) * 2 + 1];
    float sc = istd * gg[c];
    float sh = gb[c] - mean * sc;
    float4 v = *(float4*)(out + i);
    v.x = fmaxf(v.x * sc + sh, 0.f);
    v.y = fmaxf(v.y * sc + sh, 0.f);
    v.z = fmaxf(v.z * sc + sh, 0.f);
    v.w = fmaxf(v.w * sc + sh, 0.f);
    *(float4*)(out + i) = v;
}

// ---------------------------------------------------------------------------
extern "C" void kernel_launch(void* const* d_in, const int* in_sizes, int n_in,
                              void* d_out, int out_size, void* d_ws, size_t ws_size,
                              hipStream_t stream)
{
    const float* x    = (const float*)d_in[0];
    const float* offs = (const float*)d_in[1];
    const float* efw  = (const float*)d_in[2];
    const float* efb  = (const float*)d_in[3];
    const float* w1   = (const float*)d_in[4];
    const float* b1   = (const float*)d_in[5];
    const float* w2   = (const float*)d_in[6];
    const float* b2   = (const float*)d_in[7];
    const float* mw   = (const float*)d_in[8];
    const float* mb   = (const float*)d_in[9];
    const float* gg   = (const float*)d_in[10];
    const float* gb   = (const float*)d_in[11];
    float* out = (float*)d_out;

    ushort* wb    = (ushort*)d_ws;
    ushort* wbe   = wb;                          // 131072
    ushort* wb1   = wb + 131072;                 // 131072
    ushort* wbm   = wb + 262144;                 // 131072
    ushort* efp   = wb + 393216;                 // B*P*HW*C bf16
    ushort* outsb = efp + (size_t)Bx * PTS * HW * Cc;
    float*  heat  = (float*)(outsb + (size_t)Bx * HW * PTS * Cc);
    float*  stat  = heat + (size_t)Bx * PTS * HW;

    dim3 blk(256);
    k_wconv  <<<dim3(384),              blk, 0, stream>>>(efw, w1, mw, wb);
    k_ef     <<<dim3(238, 4, Bx),       blk, 0, stream>>>(x, wbe, efb, efp);
    k_heat   <<<dim3(238, PTS, Bx),     blk, 0, stream>>>(efp, wb1, b1, w2, b2, heat);
    k_sample <<<dim3(480, PTS, Bx),     blk, 0, stream>>>(efp, heat, offs, outsb);
    k_merge  <<<dim3(238, 2, Bx),       blk, 0, stream>>>(outsb, wbm, mb, out);
    k_gnstats<<<dim3(32, Bx),           blk, 0, stream>>>(out, stat);
    k_gnapply<<<dim3(Bx * Cc * HW / 4 / 256), blk, 0, stream>>>(out, stat, gg, gb);
}

// Round 3
// 311.571 us; speedup vs baseline: 2.1847x; 1.2724x over previous
//
#include <hip/hip_runtime.h>

#define BINS 5
#define PTS  2
constexpr int Bx = 2, Cc = 256, Hh = 100, Ww = 152;
constexpr int HW = Hh * Ww;          // 15200
constexpr float EPS_DIV = 1e-6f;
constexpr float GN_EPS  = 1e-5f;

typedef __attribute__((ext_vector_type(8))) short bfrag;   // 8 bf16 (4 VGPRs)
typedef __attribute__((ext_vector_type(4))) float f32x4;   // MFMA C/D

__device__ __forceinline__ ushort f2bf(float f) {
    union { float f; unsigned u; } v; v.f = f;
    unsigned r = v.u + 0x7fffu + ((v.u >> 16) & 1u);
    return (ushort)(r >> 16);
}
__device__ __forceinline__ float bf2f(ushort h) {
    union { unsigned u; float f; } v; v.u = ((unsigned)h) << 16;
    return v.f;
}

// ---------------------------------------------------------------------------
// K0: convert ef_w, hm1_w, merge_w to bf16 (each 131072 elems) + zero GN parts
// ---------------------------------------------------------------------------
__global__ __launch_bounds__(256)
void k_wconv(const float* __restrict__ efw, const float* __restrict__ w1,
             const float* __restrict__ mw, ushort* __restrict__ wb,
             float* __restrict__ part)
{
    if (blockIdx.x == 0 && threadIdx.x < 128) part[threadIdx.x] = 0.f;
    int gid = blockIdx.x * 256 + threadIdx.x;
    int e = gid * 4;                       // 393216 total elements
    int arr = e >> 17, off = e & 131071;
    const float* src = arr == 0 ? efw : (arr == 1 ? w1 : mw);
    float4 v = *(const float4*)(src + off);
    ushort4 o = { f2bf(v.x), f2bf(v.y), f2bf(v.z), f2bf(v.w) };
    *(ushort4*)(wb + e) = o;
}

// ---------------------------------------------------------------------------
// K1: efp[b][p][pix][c] (bf16) = ef_w @ x + ef_b.  MFMA 16x16x32 bf16.
// ---------------------------------------------------------------------------
__global__ __launch_bounds__(256)
void k_ef(const float* __restrict__ x, const ushort* __restrict__ wbe,
          const float* __restrict__ efb, ushort* __restrict__ efp)
{
    __shared__ ushort As[128 * 72];     // [n][k] pad 72
    __shared__ ushort Bs[64 * 72];      // [pix][k]
    const int t = threadIdx.x;
    const int wv = t >> 6, ln = t & 63;
    const int quad = ln >> 4, l16 = ln & 15;
    const int pix0 = blockIdx.x * 64;
    const int n0 = blockIdx.y * 128;
    const int b = blockIdx.z;
    const float* xb = x + (size_t)b * Cc * HW;

    f32x4 acc[2][4];
    #pragma unroll
    for (int i = 0; i < 2; i++)
        #pragma unroll
        for (int j = 0; j < 4; j++) acc[i][j] = (f32x4){0.f, 0.f, 0.f, 0.f};

    const int arow = t >> 3, acol = (t & 7) * 8;
    const int bpix = t & 63, bkg = (t >> 6) * 8;
    int pp = pix0 + bpix; if (pp > HW - 1) pp = HW - 1;

    for (int k0 = 0; k0 < 256; k0 += 64) {
        #pragma unroll
        for (int r = 0; r < 4; r++) {
            int row = arow + r * 32;
            *(uint4*)&As[row * 72 + acol] =
                *(const uint4*)&wbe[(size_t)(n0 + row) * 256 + k0 + acol];
        }
        #pragma unroll
        for (int r = 0; r < 2; r++) {
            int kc = bkg + r * 32;
            union { ushort s[8]; uint4 v; } tmp;
            #pragma unroll
            for (int j = 0; j < 8; j++)
                tmp.s[j] = f2bf(xb[(size_t)(k0 + kc + j) * HW + pp]);
            *(uint4*)&Bs[bpix * 72 + kc] = tmp.v;
        }
        __syncthreads();
        #pragma unroll
        for (int kk = 0; kk < 64; kk += 32) {
            bfrag af[2], bfr[4];
            #pragma unroll
            for (int dt = 0; dt < 2; dt++)
                af[dt] = *(const bfrag*)&As[(wv * 32 + dt * 16 + l16) * 72 + kk + quad * 8];
            #pragma unroll
            for (int pt = 0; pt < 4; pt++)
                bfr[pt] = *(const bfrag*)&Bs[(pt * 16 + l16) * 72 + kk + quad * 8];
            #pragma unroll
            for (int dt = 0; dt < 2; dt++)
                #pragma unroll
                for (int pt = 0; pt < 4; pt++)
                    acc[dt][pt] = __builtin_amdgcn_mfma_f32_16x16x32_bf16(
                        af[dt], bfr[pt], acc[dt][pt], 0, 0, 0);
        }
        __syncthreads();
    }

    // epilogue: bias, bf16, transpose via LDS (reuse As: [pix][ch] pad 136)
    float bias[2][4];
    #pragma unroll
    for (int dt = 0; dt < 2; dt++)
        #pragma unroll
        for (int r = 0; r < 4; r++)
            bias[dt][r] = efb[n0 + wv * 32 + dt * 16 + quad * 4 + r];
    #pragma unroll
    for (int dt = 0; dt < 2; dt++)
        #pragma unroll
        for (int pt = 0; pt < 4; pt++) {
            int pix = pt * 16 + l16;
            int ch = wv * 32 + dt * 16 + quad * 4;
            ushort4 o = { f2bf(acc[dt][pt][0] + bias[dt][0]),
                          f2bf(acc[dt][pt][1] + bias[dt][1]),
                          f2bf(acc[dt][pt][2] + bias[dt][2]),
                          f2bf(acc[dt][pt][3] + bias[dt][3]) };
            *(ushort4*)&As[pix * 136 + ch] = o;
        }
    __syncthreads();
    const int p = n0 >> 8, cbase = n0 & 255;
    ushort* outb = efp + (size_t)((b * PTS + p) * HW) * Cc;
    #pragma unroll
    for (int r = 0; r < 4; r++) {
        int pix = (t >> 4) + r * 16;
        int ch8 = (t & 15) * 8;
        if (pix0 + pix < HW)
            *(uint4*)&outb[(size_t)(pix0 + pix) * Cc + cbase + ch8] =
                *(const uint4*)&As[pix * 136 + ch8];
    }
}

// ---------------------------------------------------------------------------
// K2: heat[b][p][pix] = exp(sum_d w2[d]*relu(D[d][pix]+b1[d]) + b2)
// ---------------------------------------------------------------------------
__global__ __launch_bounds__(256)
void k_heat(const ushort* __restrict__ efp, const ushort* __restrict__ wb1,
            const float* __restrict__ b1, const float* __restrict__ w2,
            const float* __restrict__ b2, float* __restrict__ heat)
{
    __shared__ ushort As[256 * 72];
    __shared__ ushort Bs[64 * 72];
    __shared__ float red[4][64];
    const int t = threadIdx.x;
    const int wv = t >> 6, ln = t & 63;
    const int quad = ln >> 4, l16 = ln & 15;
    const int pix0 = blockIdx.x * 64;
    const int p = blockIdx.y;
    const int b = blockIdx.z;
    const ushort* efb_ = efp + (size_t)((b * PTS + p) * HW) * Cc;
    const ushort* w1p = wb1 + (size_t)p * Cc * Cc;

    f32x4 acc[4][4];
    #pragma unroll
    for (int i = 0; i < 4; i++)
        #pragma unroll
        for (int j = 0; j < 4; j++) acc[i][j] = (f32x4){0.f, 0.f, 0.f, 0.f};

    const int srow = t >> 3, scol = (t & 7) * 8;

    for (int k0 = 0; k0 < 256; k0 += 64) {
        #pragma unroll
        for (int r = 0; r < 8; r++) {
            int row = srow + r * 32;
            *(uint4*)&As[row * 72 + scol] =
                *(const uint4*)&w1p[(size_t)row * 256 + k0 + scol];
        }
        #pragma unroll
        for (int r = 0; r < 2; r++) {
            int row = srow + r * 32;
            int pp = pix0 + row; if (pp > HW - 1) pp = HW - 1;
            *(uint4*)&Bs[row * 72 + scol] =
                *(const uint4*)&efb_[(size_t)pp * Cc + k0 + scol];
        }
        __syncthreads();
        #pragma unroll
        for (int kk = 0; kk < 64; kk += 32) {
            bfrag af[4], bfr[4];
            #pragma unroll
            for (int dt = 0; dt < 4; dt++)
                af[dt] = *(const bfrag*)&As[(wv * 64 + dt * 16 + l16) * 72 + kk + quad * 8];
            #pragma unroll
            for (int pt = 0; pt < 4; pt++)
                bfr[pt] = *(const bfrag*)&Bs[(pt * 16 + l16) * 72 + kk + quad * 8];
            #pragma unroll
            for (int dt = 0; dt < 4; dt++)
                #pragma unroll
                for (int pt = 0; pt < 4; pt++)
                    acc[dt][pt] = __builtin_amdgcn_mfma_f32_16x16x32_bf16(
                        af[dt], bfr[pt], acc[dt][pt], 0, 0, 0);
        }
        __syncthreads();
    }

    const float* b1p = b1 + p * 256;
    const float* w2p = w2 + p * 256;
    float s[4] = {0.f, 0.f, 0.f, 0.f};
    #pragma unroll
    for (int dt = 0; dt < 4; dt++) {
        int chb = wv * 64 + dt * 16 + quad * 4;
        float bb[4], ww[4];
        #pragma unroll
        for (int r = 0; r < 4; r++) { bb[r] = b1p[chb + r]; ww[r] = w2p[chb + r]; }
        #pragma unroll
        for (int pt = 0; pt < 4; pt++)
            #pragma unroll
            for (int r = 0; r < 4; r++) {
                float h = acc[dt][pt][r] + bb[r];
                h = h > 0.f ? h : 0.f;
                s[pt] += ww[r] * h;
            }
    }
    #pragma unroll
    for (int pt = 0; pt < 4; pt++) {
        s[pt] += __shfl_xor(s[pt], 16);
        s[pt] += __shfl_xor(s[pt], 32);
    }
    if (ln < 16) {
        #pragma unroll
        for (int pt = 0; pt < 4; pt++) red[wv][pt * 16 + ln] = s[pt];
    }
    __syncthreads();
    if (t < 64) {
        float v = red[0][t] + red[1][t] + red[2][t] + red[3][t] + b2[p];
        int m = pix0 + t;
        if (m < HW) heat[(size_t)(b * PTS + p) * HW + m] = expf(v);
    }
}

// ---------------------------------------------------------------------------
// K3: deformable sampling. Lane = channel PAIR (32-bit gathers), 2 pixels
// in flight (128 lanes cover 256 ch). XCD-swizzled pixel bands.
// ---------------------------------------------------------------------------
__global__ __launch_bounds__(256)
void k_sample(const ushort* __restrict__ efp, const float* __restrict__ heat,
              const float* __restrict__ offs, ushort* __restrict__ outs)
{
    __shared__ float s_wh[32][20];
    __shared__ int   s_idx[32][20];
    const int t = threadIdx.x;
    const int bid = blockIdx.x;
    const int nx = (bid & 7) * 60 + (bid >> 3);   // XCD-contiguous bands
    if (nx >= 475) return;
    const int m0 = nx * 32;
    const int p = blockIdx.y;
    const int b = blockIdx.z;
    const float* heat_bp = heat + (size_t)(b * PTS + p) * HW;

    if (t < 32 * BINS) {
        int j = t / BINS, k = t % BINS;
        int hw = m0 + j;
        int hh = hw / Ww, ww = hw % Ww;
        int chy = (p * BINS + k) * 2;
        float oy = offs[((size_t)b * (PTS * BINS * 2) + chy)     * HW + hw];
        float ox = offs[((size_t)b * (PTS * BINS * 2) + chy + 1) * HW + hw];
        float ysf = (float)hh + oy;
        float xsf = (float)ww + ox;
        float y0 = floorf(ysf), x0 = floorf(xsf);
        #pragma unroll
        for (int dy = 0; dy < 2; dy++)
            #pragma unroll
            for (int dx = 0; dx < 2; dx++) {
                float yi = y0 + dy, xi = x0 + dx;
                float wgt = (1.f - fabsf(ysf - yi)) * (1.f - fabsf(xsf - xi));
                bool valid = (yi >= 0.f) && (yi <= (float)(Hh - 1)) &&
                             (xi >= 0.f) && (xi <= (float)(Ww - 1));
                int yc = (int)yi; yc = yc < 0 ? 0 : (yc > Hh - 1 ? Hh - 1 : yc);
                int xc = (int)xi; xc = xc < 0 ? 0 : (xc > Ww - 1 ? Ww - 1 : xc);
                int idx = yc * Ww + xc;
                float wh = valid ? wgt * heat_bp[idx] : 0.f;
                s_wh[j][k * 4 + dy * 2 + dx]  = wh;
                s_idx[j][k * 4 + dy * 2 + dx] = idx;
            }
    }
    __syncthreads();
    if (t < 32) {
        float s = 0.f;
        #pragma unroll
        for (int u = 0; u < 20; u++) s += s_wh[t][u];
        float inv = 1.f / (s + EPS_DIV);
        #pragma unroll
        for (int u = 0; u < 20; u++) s_wh[t][u] *= inv;
    }
    __syncthreads();

    // phase 2: lane = channel pair, two pixels concurrently
    const int c2 = (t & 127) * 2;
    const int jj = t >> 7;
    const ushort* ef = efp + (size_t)((b * PTS + p) * HW) * Cc + c2;
    ushort* ob = outs + ((size_t)(b * HW + m0)) * (PTS * Cc) + p * Cc + c2;
    for (int j = jj; j < 32; j += 2) {
        float a0 = 0.f, a1 = 0.f;
        #pragma unroll
        for (int u = 0; u < 20; u++) {
            float w = s_wh[j][u];
            unsigned v = *(const unsigned*)(ef + (size_t)s_idx[j][u] * Cc);
            a0 += w * bf2f((ushort)(v & 0xffffu));
            a1 += w * bf2f((ushort)(v >> 16));
        }
        unsigned o = (unsigned)f2bf(a0) | ((unsigned)f2bf(a1) << 16);
        *(unsigned*)(ob + (size_t)j * (PTS * Cc)) = o;
    }
}

// ---------------------------------------------------------------------------
// K4: out[b][c][pix] (fp32) = merge_w @ outs + merge_b, + fused GN partials.
// ---------------------------------------------------------------------------
__global__ __launch_bounds__(256)
void k_merge(const ushort* __restrict__ outs, const ushort* __restrict__ wbm,
             const float* __restrict__ mb, float* __restrict__ out,
             float* __restrict__ part)
{
    __shared__ ushort As[128 * 72];
    __shared__ ushort Bs[64 * 72];
    const int t = threadIdx.x;
    const int wv = t >> 6, ln = t & 63;
    const int quad = ln >> 4, l16 = ln & 15;
    const int pix0 = blockIdx.x * 64;
    const int n0 = blockIdx.y * 128;
    const int b = blockIdx.z;
    const ushort* ob = outs + (size_t)b * HW * (PTS * Cc);

    f32x4 acc[2][4];
    #pragma unroll
    for (int i = 0; i < 2; i++)
        #pragma unroll
        for (int j = 0; j < 4; j++) acc[i][j] = (f32x4){0.f, 0.f, 0.f, 0.f};

    const int srow = t >> 3, scol = (t & 7) * 8;

    for (int k0 = 0; k0 < 512; k0 += 64) {
        #pragma unroll
        for (int r = 0; r < 4; r++) {
            int row = srow + r * 32;
            *(uint4*)&As[row * 72 + scol] =
                *(const uint4*)&wbm[(size_t)(n0 + row) * 512 + k0 + scol];
        }
        #pragma unroll
        for (int r = 0; r < 2; r++) {
            int row = srow + r * 32;
            int pp = pix0 + row; if (pp > HW - 1) pp = HW - 1;
            *(uint4*)&Bs[row * 72 + scol] =
                *(const uint4*)&ob[(size_t)pp * (PTS * Cc) + k0 + scol];
        }
        __syncthreads();
        #pragma unroll
        for (int kk = 0; kk < 64; kk += 32) {
            bfrag af[2], bfr[4];
            #pragma unroll
            for (int dt = 0; dt < 2; dt++)
                af[dt] = *(const bfrag*)&As[(wv * 32 + dt * 16 + l16) * 72 + kk + quad * 8];
            #pragma unroll
            for (int pt = 0; pt < 4; pt++)
                bfr[pt] = *(const bfrag*)&Bs[(pt * 16 + l16) * 72 + kk + quad * 8];
            #pragma unroll
            for (int dt = 0; dt < 2; dt++)
                #pragma unroll
                for (int pt = 0; pt < 4; pt++)
                    acc[dt][pt] = __builtin_amdgcn_mfma_f32_16x16x32_bf16(
                        af[dt], bfr[pt], acc[dt][pt], 0, 0, 0);
        }
        __syncthreads();
    }

    float bias[2][4];
    #pragma unroll
    for (int dt = 0; dt < 2; dt++)
        #pragma unroll
        for (int r = 0; r < 4; r++)
            bias[dt][r] = mb[n0 + wv * 32 + dt * 16 + quad * 4 + r];

    float sacc[2] = {0.f, 0.f}, qacc[2] = {0.f, 0.f};
    #pragma unroll
    for (int dt = 0; dt < 2; dt++)
        #pragma unroll
        for (int pt = 0; pt < 4; pt++) {
            int ch = n0 + wv * 32 + dt * 16 + quad * 4;
            int pix = pix0 + pt * 16 + l16;
            if (pix < HW) {
                #pragma unroll
                for (int r = 0; r < 4; r++) {
                    float v = acc[dt][pt][r] + bias[dt][r];
                    out[((size_t)b * Cc + ch + r) * HW + pix] = v;
                    sacc[dt] += v; qacc[dt] += v * v;
                }
            }
        }
    // reduce over lanes 0..31 / 32..63 (each half is one 8-ch group per dt)
    #pragma unroll
    for (int dt = 0; dt < 2; dt++) {
        #pragma unroll
        for (int off = 1; off <= 16; off <<= 1) {
            sacc[dt] += __shfl_xor(sacc[dt], off);
            qacc[dt] += __shfl_xor(qacc[dt], off);
        }
        if ((ln & 31) == 0) {
            int g = (n0 >> 3) + wv * 4 + dt * 2 + (ln >> 5);
            atomicAdd(&part[(b * 32 + g) * 2 + 0], sacc[dt]);
            atomicAdd(&part[(b * 32 + g) * 2 + 1], qacc[dt]);
        }
    }
}

// ---------------------------------------------------------------------------
// K5: finalize GN stats (64 groups total)
// ---------------------------------------------------------------------------
__global__ __launch_bounds__(64)
void k_gnfinal(const float* __restrict__ part, float* __restrict__ statf)
{
    int i = threadIdx.x;
    float s = part[i * 2 + 0], q = part[i * 2 + 1];
    const float n = 8.f * HW;
    float mean = s / n;
    float var  = q / n - mean * mean;
    statf[i * 2 + 0] = mean;
    statf[i * 2 + 1] = rsqrtf(var + GN_EPS);
}

// ---------------------------------------------------------------------------
// K6: apply GN scale/shift + ReLU in place
// ---------------------------------------------------------------------------
__global__ __launch_bounds__(256)
void k_gnapply(float* __restrict__ out, const float* __restrict__ statf,
               const float* __restrict__ gg, const float* __restrict__ gb)
{
    const int i4 = blockIdx.x * 256 + threadIdx.x;
    const int total4 = Bx * Cc * HW / 4;
    if (i4 >= total4) return;
    const int i = i4 * 4;
    const int CHW = Cc * HW;
    const int b = i / CHW;
    const int r = i - b * CHW;
    const int c = r / HW;
    const int g = c >> 3;
    float mean = statf[(b * 32 + g) * 2 + 0];
    float istd = statf[(b * 32 + g) * 2 + 1];
    float sc = istd * gg[c];
    float sh = gb[c] - mean * sc;
    float4 v = *(float4*)(out + i);
    v.x = fmaxf(v.x * sc + sh, 0.f);
    v.y = fmaxf(v.y * sc + sh, 0.f);
    v.z = fmaxf(v.z * sc + sh, 0.f);
    v.w = fmaxf(v.w * sc + sh, 0.f);
    *(float4*)(out + i) = v;
}

// ---------------------------------------------------------------------------
extern "C" void kernel_launch(void* const* d_in, const int* in_sizes, int n_in,
                              void* d_out, int out_size, void* d_ws, size_t ws_size,
                              hipStream_t stream)
{
    const float* x    = (const float*)d_in[0];
    const float* offs = (const float*)d_in[1];
    const float* efw  = (const float*)d_in[2];
    const float* efb  = (const float*)d_in[3];
    const float* w1   = (const float*)d_in[4];
    const float* b1   = (const float*)d_in[5];
    const float* w2   = (const float*)d_in[6];
    const float* b2   = (const float*)d_in[7];
    const float* mw   = (const float*)d_in[8];
    const float* mb   = (const float*)d_in[9];
    const float* gg   = (const float*)d_in[10];
    const float* gb   = (const float*)d_in[11];
    float* out = (float*)d_out;

    ushort* wb    = (ushort*)d_ws;
    ushort* wbe   = wb;                          // 131072
    ushort* wb1   = wb + 131072;                 // 131072
    ushort* wbm   = wb + 262144;                 // 131072
    ushort* efp   = wb + 393216;                 // B*P*HW*C bf16
    ushort* outsb = efp + (size_t)Bx * PTS * HW * Cc;
    float*  heat  = (float*)(outsb + (size_t)Bx * HW * PTS * Cc);
    float*  part  = heat + (size_t)Bx * PTS * HW;   // 128 floats
    float*  statf = part + 128;                     // 128 floats

    dim3 blk(256);
    k_wconv  <<<dim3(384),              blk, 0, stream>>>(efw, w1, mw, wb, part);
    k_ef     <<<dim3(238, 4, Bx),       blk, 0, stream>>>(x, wbe, efb, efp);
    k_heat   <<<dim3(238, PTS, Bx),     blk, 0, stream>>>(efp, wb1, b1, w2, b2, heat);
    k_sample <<<dim3(480, PTS, Bx),     blk, 0, stream>>>(efp, heat, offs, outsb);
    k_merge  <<<dim3(238, 2, Bx),       blk, 0, stream>>>(outsb, wbm, mb, out, part);
    k_gnfinal<<<dim3(1), dim3(64),      0, stream>>>(part, statf);
    k_gnapply<<<dim3(Bx * Cc * HW / 4 / 256), blk, 0, stream>>>(out, statf, gg, gb);
}

// Round 4
// 265.371 us; speedup vs baseline: 2.5651x; 1.1741x over previous
//
#include <hip/hip_runtime.h>

#define BINS 5
#define PTS  2
constexpr int Bx = 2, Cc = 256, Hh = 100, Ww = 152;
constexpr int HW = Hh * Ww;          // 15200
constexpr float EPS_DIV = 1e-6f;
constexpr float GN_EPS  = 1e-5f;

typedef __attribute__((ext_vector_type(8))) short bfrag;   // 8 bf16 (4 VGPRs)
typedef __attribute__((ext_vector_type(4))) float f32x4;   // MFMA C/D

__device__ __forceinline__ ushort f2bf(float f) {
    union { float f; unsigned u; } v; v.f = f;
    unsigned r = v.u + 0x7fffu + ((v.u >> 16) & 1u);
    return (ushort)(r >> 16);
}
__device__ __forceinline__ float bf2f(ushort h) {
    union { unsigned u; float f; } v; v.u = ((unsigned)h) << 16;
    return v.f;
}
__device__ __forceinline__ float bflo(unsigned u) {
    return __uint_as_float(u << 16);
}
__device__ __forceinline__ float bfhi(unsigned u) {
    return __uint_as_float(u & 0xffff0000u);
}
__device__ __forceinline__ unsigned pack2(float a, float b) {
    return (unsigned)f2bf(a) | ((unsigned)f2bf(b) << 16);
}

// ---------------------------------------------------------------------------
// K0: convert ef_w, hm1_w, merge_w to bf16 (each 131072 elems) + zero GN parts
// ---------------------------------------------------------------------------
__global__ __launch_bounds__(256)
void k_wconv(const float* __restrict__ efw, const float* __restrict__ w1,
             const float* __restrict__ mw, ushort* __restrict__ wb,
             float* __restrict__ part)
{
    if (blockIdx.x == 0 && threadIdx.x < 128) part[threadIdx.x] = 0.f;
    int gid = blockIdx.x * 256 + threadIdx.x;
    int e = gid * 4;                       // 393216 total elements
    int arr = e >> 17, off = e & 131071;
    const float* src = arr == 0 ? efw : (arr == 1 ? w1 : mw);
    float4 v = *(const float4*)(src + off);
    ushort4 o = { f2bf(v.x), f2bf(v.y), f2bf(v.z), f2bf(v.w) };
    *(ushort4*)(wb + e) = o;
}

// ---------------------------------------------------------------------------
// K1: efp[b][p][pix][c] (bf16) = ef_w @ x + ef_b.  MFMA 16x16x32 bf16.
// ---------------------------------------------------------------------------
__global__ __launch_bounds__(256)
void k_ef(const float* __restrict__ x, const ushort* __restrict__ wbe,
          const float* __restrict__ efb, ushort* __restrict__ efp)
{
    __shared__ ushort As[128 * 72];     // [n][k] pad 72
    __shared__ ushort Bs[64 * 72];      // [pix][k]
    const int t = threadIdx.x;
    const int wv = t >> 6, ln = t & 63;
    const int quad = ln >> 4, l16 = ln & 15;
    const int pix0 = blockIdx.x * 64;
    const int n0 = blockIdx.y * 128;
    const int b = blockIdx.z;
    const float* xb = x + (size_t)b * Cc * HW;

    f32x4 acc[2][4];
    #pragma unroll
    for (int i = 0; i < 2; i++)
        #pragma unroll
        for (int j = 0; j < 4; j++) acc[i][j] = (f32x4){0.f, 0.f, 0.f, 0.f};

    const int arow = t >> 3, acol = (t & 7) * 8;
    const int bpix = t & 63, bkg = (t >> 6) * 8;
    int pp = pix0 + bpix; if (pp > HW - 1) pp = HW - 1;

    for (int k0 = 0; k0 < 256; k0 += 64) {
        #pragma unroll
        for (int r = 0; r < 4; r++) {
            int row = arow + r * 32;
            *(uint4*)&As[row * 72 + acol] =
                *(const uint4*)&wbe[(size_t)(n0 + row) * 256 + k0 + acol];
        }
        #pragma unroll
        for (int r = 0; r < 2; r++) {
            int kc = bkg + r * 32;
            union { ushort s[8]; uint4 v; } tmp;
            #pragma unroll
            for (int j = 0; j < 8; j++)
                tmp.s[j] = f2bf(xb[(size_t)(k0 + kc + j) * HW + pp]);
            *(uint4*)&Bs[bpix * 72 + kc] = tmp.v;
        }
        __syncthreads();
        #pragma unroll
        for (int kk = 0; kk < 64; kk += 32) {
            bfrag af[2], bfr[4];
            #pragma unroll
            for (int dt = 0; dt < 2; dt++)
                af[dt] = *(const bfrag*)&As[(wv * 32 + dt * 16 + l16) * 72 + kk + quad * 8];
            #pragma unroll
            for (int pt = 0; pt < 4; pt++)
                bfr[pt] = *(const bfrag*)&Bs[(pt * 16 + l16) * 72 + kk + quad * 8];
            #pragma unroll
            for (int dt = 0; dt < 2; dt++)
                #pragma unroll
                for (int pt = 0; pt < 4; pt++)
                    acc[dt][pt] = __builtin_amdgcn_mfma_f32_16x16x32_bf16(
                        af[dt], bfr[pt], acc[dt][pt], 0, 0, 0);
        }
        __syncthreads();
    }

    // epilogue: bias, bf16, transpose via LDS (reuse As: [pix][ch] pad 136)
    float bias[2][4];
    #pragma unroll
    for (int dt = 0; dt < 2; dt++)
        #pragma unroll
        for (int r = 0; r < 4; r++)
            bias[dt][r] = efb[n0 + wv * 32 + dt * 16 + quad * 4 + r];
    #pragma unroll
    for (int dt = 0; dt < 2; dt++)
        #pragma unroll
        for (int pt = 0; pt < 4; pt++) {
            int pix = pt * 16 + l16;
            int ch = wv * 32 + dt * 16 + quad * 4;
            ushort4 o = { f2bf(acc[dt][pt][0] + bias[dt][0]),
                          f2bf(acc[dt][pt][1] + bias[dt][1]),
                          f2bf(acc[dt][pt][2] + bias[dt][2]),
                          f2bf(acc[dt][pt][3] + bias[dt][3]) };
            *(ushort4*)&As[pix * 136 + ch] = o;
        }
    __syncthreads();
    const int p = n0 >> 8, cbase = n0 & 255;
    ushort* outb = efp + (size_t)((b * PTS + p) * HW) * Cc;
    #pragma unroll
    for (int r = 0; r < 4; r++) {
        int pix = (t >> 4) + r * 16;
        int ch8 = (t & 15) * 8;
        if (pix0 + pix < HW)
            *(uint4*)&outb[(size_t)(pix0 + pix) * Cc + cbase + ch8] =
                *(const uint4*)&As[pix * 136 + ch8];
    }
}

// ---------------------------------------------------------------------------
// K2: heat[b][p][pix] = exp(sum_d w2[d]*relu(D[d][pix]+b1[d]) + b2)
// ---------------------------------------------------------------------------
__global__ __launch_bounds__(256)
void k_heat(const ushort* __restrict__ efp, const ushort* __restrict__ wb1,
            const float* __restrict__ b1, const float* __restrict__ w2,
            const float* __restrict__ b2, float* __restrict__ heat)
{
    __shared__ ushort As[256 * 72];
    __shared__ ushort Bs[64 * 72];
    __shared__ float red[4][64];
    const int t = threadIdx.x;
    const int wv = t >> 6, ln = t & 63;
    const int quad = ln >> 4, l16 = ln & 15;
    const int pix0 = blockIdx.x * 64;
    const int p = blockIdx.y;
    const int b = blockIdx.z;
    const ushort* efb_ = efp + (size_t)((b * PTS + p) * HW) * Cc;
    const ushort* w1p = wb1 + (size_t)p * Cc * Cc;

    f32x4 acc[4][4];
    #pragma unroll
    for (int i = 0; i < 4; i++)
        #pragma unroll
        for (int j = 0; j < 4; j++) acc[i][j] = (f32x4){0.f, 0.f, 0.f, 0.f};

    const int srow = t >> 3, scol = (t & 7) * 8;

    for (int k0 = 0; k0 < 256; k0 += 64) {
        #pragma unroll
        for (int r = 0; r < 8; r++) {
            int row = srow + r * 32;
            *(uint4*)&As[row * 72 + scol] =
                *(const uint4*)&w1p[(size_t)row * 256 + k0 + scol];
        }
        #pragma unroll
        for (int r = 0; r < 2; r++) {
            int row = srow + r * 32;
            int pp = pix0 + row; if (pp > HW - 1) pp = HW - 1;
            *(uint4*)&Bs[row * 72 + scol] =
                *(const uint4*)&efb_[(size_t)pp * Cc + k0 + scol];
        }
        __syncthreads();
        #pragma unroll
        for (int kk = 0; kk < 64; kk += 32) {
            bfrag af[4], bfr[4];
            #pragma unroll
            for (int dt = 0; dt < 4; dt++)
                af[dt] = *(const bfrag*)&As[(wv * 64 + dt * 16 + l16) * 72 + kk + quad * 8];
            #pragma unroll
            for (int pt = 0; pt < 4; pt++)
                bfr[pt] = *(const bfrag*)&Bs[(pt * 16 + l16) * 72 + kk + quad * 8];
            #pragma unroll
            for (int dt = 0; dt < 4; dt++)
                #pragma unroll
                for (int pt = 0; pt < 4; pt++)
                    acc[dt][pt] = __builtin_amdgcn_mfma_f32_16x16x32_bf16(
                        af[dt], bfr[pt], acc[dt][pt], 0, 0, 0);
        }
        __syncthreads();
    }

    const float* b1p = b1 + p * 256;
    const float* w2p = w2 + p * 256;
    float s[4] = {0.f, 0.f, 0.f, 0.f};
    #pragma unroll
    for (int dt = 0; dt < 4; dt++) {
        int chb = wv * 64 + dt * 16 + quad * 4;
        float bb[4], ww[4];
        #pragma unroll
        for (int r = 0; r < 4; r++) { bb[r] = b1p[chb + r]; ww[r] = w2p[chb + r]; }
        #pragma unroll
        for (int pt = 0; pt < 4; pt++)
            #pragma unroll
            for (int r = 0; r < 4; r++) {
                float h = acc[dt][pt][r] + bb[r];
                h = h > 0.f ? h : 0.f;
                s[pt] += ww[r] * h;
            }
    }
    #pragma unroll
    for (int pt = 0; pt < 4; pt++) {
        s[pt] += __shfl_xor(s[pt], 16);
        s[pt] += __shfl_xor(s[pt], 32);
    }
    if (ln < 16) {
        #pragma unroll
        for (int pt = 0; pt < 4; pt++) red[wv][pt * 16 + ln] = s[pt];
    }
    __syncthreads();
    if (t < 64) {
        float v = red[0][t] + red[1][t] + red[2][t] + red[3][t] + b2[p];
        int m = pix0 + t;
        if (m < HW) heat[(size_t)(b * PTS + p) * HW + m] = expf(v);
    }
}

// ---------------------------------------------------------------------------
// K3: deformable sampling. Lane = 4-channel group (uint2 gathers, 64 lanes =
// 256 ch = 512 B/wave). Wave owns 8 pixels, unrolled x2 for ~40 loads in
// flight. (weight, byte-offset) packed in one LDS uint2. XCD-swizzled bands.
// ---------------------------------------------------------------------------
__global__ __launch_bounds__(256)
void k_sample(const ushort* __restrict__ efp, const float* __restrict__ heat,
              const float* __restrict__ offs, ushort* __restrict__ outs)
{
    __shared__ uint2 s_wo[32][20];      // {bitcast(weight), byteoff = idx<<9}
    const int t = threadIdx.x;
    const int bid = blockIdx.x;
    const int nx = (bid & 7) * 60 + (bid >> 3);   // XCD-contiguous bands
    if (nx >= 475) return;
    const int m0 = nx * 32;
    const int p = blockIdx.y;
    const int b = blockIdx.z;
    const float* heat_bp = heat + (size_t)(b * PTS + p) * HW;

    if (t < 32 * BINS) {
        int j = t / BINS, k = t % BINS;
        int hw = m0 + j;
        int hh = hw / Ww, ww = hw % Ww;
        int chy = (p * BINS + k) * 2;
        float oy = offs[((size_t)b * (PTS * BINS * 2) + chy)     * HW + hw];
        float ox = offs[((size_t)b * (PTS * BINS * 2) + chy + 1) * HW + hw];
        float ysf = (float)hh + oy;
        float xsf = (float)ww + ox;
        float y0 = floorf(ysf), x0 = floorf(xsf);
        #pragma unroll
        for (int dy = 0; dy < 2; dy++)
            #pragma unroll
            for (int dx = 0; dx < 2; dx++) {
                float yi = y0 + dy, xi = x0 + dx;
                float wgt = (1.f - fabsf(ysf - yi)) * (1.f - fabsf(xsf - xi));
                bool valid = (yi >= 0.f) && (yi <= (float)(Hh - 1)) &&
                             (xi >= 0.f) && (xi <= (float)(Ww - 1));
                int yc = (int)yi; yc = yc < 0 ? 0 : (yc > Hh - 1 ? Hh - 1 : yc);
                int xc = (int)xi; xc = xc < 0 ? 0 : (xc > Ww - 1 ? Ww - 1 : xc);
                int idx = yc * Ww + xc;
                float wh = valid ? wgt * heat_bp[idx] : 0.f;
                s_wo[j][k * 4 + dy * 2 + dx] =
                    make_uint2(__float_as_uint(wh), (unsigned)idx << 9);
            }
    }
    __syncthreads();
    if (t < 32) {
        float s = 0.f;
        #pragma unroll
        for (int u = 0; u < 20; u++) s += __uint_as_float(s_wo[t][u].x);
        float inv = 1.f / (s + EPS_DIV);
        #pragma unroll
        for (int u = 0; u < 20; u++)
            s_wo[t][u].x = __float_as_uint(__uint_as_float(s_wo[t][u].x) * inv);
    }
    __syncthreads();

    // phase 2: lane = 4-channel group; wave wv owns pixels wv*8 .. wv*8+7
    const int wv = t >> 6, ln = t & 63;
    const char* efbase = (const char*)(efp + (size_t)((b * PTS + p) * HW) * Cc)
                         + ln * 8;
    ushort* ob = outs + ((size_t)(b * HW + m0)) * (PTS * Cc) + p * Cc + ln * 4;
    #pragma unroll
    for (int i = 0; i < 8; i += 2) {
        const int j0 = wv * 8 + i, j1 = j0 + 1;
        float a0[4] = {0.f, 0.f, 0.f, 0.f};
        float a1[4] = {0.f, 0.f, 0.f, 0.f};
        #pragma unroll
        for (int u = 0; u < 20; u++) {
            uint2 wo0 = s_wo[j0][u];
            uint2 wo1 = s_wo[j1][u];
            uint2 v0 = *(const uint2*)(efbase + wo0.y);
            uint2 v1 = *(const uint2*)(efbase + wo1.y);
            float w0 = __uint_as_float(wo0.x);
            float w1 = __uint_as_float(wo1.x);
            a0[0] += w0 * bflo(v0.x); a0[1] += w0 * bfhi(v0.x);
            a0[2] += w0 * bflo(v0.y); a0[3] += w0 * bfhi(v0.y);
            a1[0] += w1 * bflo(v1.x); a1[1] += w1 * bfhi(v1.x);
            a1[2] += w1 * bflo(v1.y); a1[3] += w1 * bfhi(v1.y);
        }
        uint2 o0 = make_uint2(pack2(a0[0], a0[1]), pack2(a0[2], a0[3]));
        uint2 o1 = make_uint2(pack2(a1[0], a1[1]), pack2(a1[2], a1[3]));
        *(uint2*)(ob + (size_t)j0 * (PTS * Cc)) = o0;
        *(uint2*)(ob + (size_t)j1 * (PTS * Cc)) = o1;
    }
}

// ---------------------------------------------------------------------------
// K4: out[b][c][pix] (fp32) = merge_w @ outs + merge_b, + fused GN partials.
// ---------------------------------------------------------------------------
__global__ __launch_bounds__(256)
void k_merge(const ushort* __restrict__ outs, const ushort* __restrict__ wbm,
             const float* __restrict__ mb, float* __restrict__ out,
             float* __restrict__ part)
{
    __shared__ ushort As[128 * 72];
    __shared__ ushort Bs[64 * 72];
    const int t = threadIdx.x;
    const int wv = t >> 6, ln = t & 63;
    const int quad = ln >> 4, l16 = ln & 15;
    const int pix0 = blockIdx.x * 64;
    const int n0 = blockIdx.y * 128;
    const int b = blockIdx.z;
    const ushort* ob = outs + (size_t)b * HW * (PTS * Cc);

    f32x4 acc[2][4];
    #pragma unroll
    for (int i = 0; i < 2; i++)
        #pragma unroll
        for (int j = 0; j < 4; j++) acc[i][j] = (f32x4){0.f, 0.f, 0.f, 0.f};

    const int srow = t >> 3, scol = (t & 7) * 8;

    for (int k0 = 0; k0 < 512; k0 += 64) {
        #pragma unroll
        for (int r = 0; r < 4; r++) {
            int row = srow + r * 32;
            *(uint4*)&As[row * 72 + scol] =
                *(const uint4*)&wbm[(size_t)(n0 + row) * 512 + k0 + scol];
        }
        #pragma unroll
        for (int r = 0; r < 2; r++) {
            int row = srow + r * 32;
            int pp = pix0 + row; if (pp > HW - 1) pp = HW - 1;
            *(uint4*)&Bs[row * 72 + scol] =
                *(const uint4*)&ob[(size_t)pp * (PTS * Cc) + k0 + scol];
        }
        __syncthreads();
        #pragma unroll
        for (int kk = 0; kk < 64; kk += 32) {
            bfrag af[2], bfr[4];
            #pragma unroll
            for (int dt = 0; dt < 2; dt++)
                af[dt] = *(const bfrag*)&As[(wv * 32 + dt * 16 + l16) * 72 + kk + quad * 8];
            #pragma unroll
            for (int pt = 0; pt < 4; pt++)
                bfr[pt] = *(const bfrag*)&Bs[(pt * 16 + l16) * 72 + kk + quad * 8];
            #pragma unroll
            for (int dt = 0; dt < 2; dt++)
                #pragma unroll
                for (int pt = 0; pt < 4; pt++)
                    acc[dt][pt] = __builtin_amdgcn_mfma_f32_16x16x32_bf16(
                        af[dt], bfr[pt], acc[dt][pt], 0, 0, 0);
        }
        __syncthreads();
    }

    float bias[2][4];
    #pragma unroll
    for (int dt = 0; dt < 2; dt++)
        #pragma unroll
        for (int r = 0; r < 4; r++)
            bias[dt][r] = mb[n0 + wv * 32 + dt * 16 + quad * 4 + r];

    float sacc[2] = {0.f, 0.f}, qacc[2] = {0.f, 0.f};
    #pragma unroll
    for (int dt = 0; dt < 2; dt++)
        #pragma unroll
        for (int pt = 0; pt < 4; pt++) {
            int ch = n0 + wv * 32 + dt * 16 + quad * 4;
            int pix = pix0 + pt * 16 + l16;
            if (pix < HW) {
                #pragma unroll
                for (int r = 0; r < 4; r++) {
                    float v = acc[dt][pt][r] + bias[dt][r];
                    out[((size_t)b * Cc + ch + r) * HW + pix] = v;
                    sacc[dt] += v; qacc[dt] += v * v;
                }
            }
        }
    // reduce over lanes 0..31 / 32..63 (each half is one 8-ch group per dt)
    #pragma unroll
    for (int dt = 0; dt < 2; dt++) {
        #pragma unroll
        for (int off = 1; off <= 16; off <<= 1) {
            sacc[dt] += __shfl_xor(sacc[dt], off);
            qacc[dt] += __shfl_xor(qacc[dt], off);
        }
        if ((ln & 31) == 0) {
            int g = (n0 >> 3) + wv * 4 + dt * 2 + (ln >> 5);
            atomicAdd(&part[(b * 32 + g) * 2 + 0], sacc[dt]);
            atomicAdd(&part[(b * 32 + g) * 2 + 1], qacc[dt]);
        }
    }
}

// ---------------------------------------------------------------------------
// K5: finalize GN stats (64 groups total)
// ---------------------------------------------------------------------------
__global__ __launch_bounds__(64)
void k_gnfinal(const float* __restrict__ part, float* __restrict__ statf)
{
    int i = threadIdx.x;
    float s = part[i * 2 + 0], q = part[i * 2 + 1];
    const float n = 8.f * HW;
    float mean = s / n;
    float var  = q / n - mean * mean;
    statf[i * 2 + 0] = mean;
    statf[i * 2 + 1] = rsqrtf(var + GN_EPS);
}

// ---------------------------------------------------------------------------
// K6: apply GN scale/shift + ReLU in place
// ---------------------------------------------------------------------------
__global__ __launch_bounds__(256)
void k_gnapply(float* __restrict__ out, const float* __restrict__ statf,
               const float* __restrict__ gg, const float* __restrict__ gb)
{
    const int i4 = blockIdx.x * 256 + threadIdx.x;
    const int total4 = Bx * Cc * HW / 4;
    if (i4 >= total4) return;
    const int i = i4 * 4;
    const int CHW = Cc * HW;
    const int b = i / CHW;
    const int r = i - b * CHW;
    const int c = r / HW;
    const int g = c >> 3;
    float mean = statf[(b * 32 + g) * 2 + 0];
    float istd = statf[(b * 32 + g) * 2 + 1];
    float sc = istd * gg[c];
    float sh = gb[c] - mean * sc;
    float4 v = *(float4*)(out + i);
    v.x = fmaxf(v.x * sc + sh, 0.f);
    v.y = fmaxf(v.y * sc + sh, 0.f);
    v.z = fmaxf(v.z * sc + sh, 0.f);
    v.w = fmaxf(v.w * sc + sh, 0.f);
    *(float4*)(out + i) = v;
}

// ---------------------------------------------------------------------------
extern "C" void kernel_launch(void* const* d_in, const int* in_sizes, int n_in,
                              void* d_out, int out_size, void* d_ws, size_t ws_size,
                              hipStream_t stream)
{
    const float* x    = (const float*)d_in[0];
    const float* offs = (const float*)d_in[1];
    const float* efw  = (const float*)d_in[2];
    const float* efb  = (const float*)d_in[3];
    const float* w1   = (const float*)d_in[4];
    const float* b1   = (const float*)d_in[5];
    const float* w2   = (const float*)d_in[6];
    const float* b2   = (const float*)d_in[7];
    const float* mw   = (const float*)d_in[8];
    const float* mb   = (const float*)d_in[9];
    const float* gg   = (const float*)d_in[10];
    const float* gb   = (const float*)d_in[11];
    float* out = (float*)d_out;

    ushort* wb    = (ushort*)d_ws;
    ushort* wbe   = wb;                          // 131072
    ushort* wb1   = wb + 131072;                 // 131072
    ushort* wbm   = wb + 262144;                 // 131072
    ushort* efp   = wb + 393216;                 // B*P*HW*C bf16
    ushort* outsb = efp + (size_t)Bx * PTS * HW * Cc;
    float*  heat  = (float*)(outsb + (size_t)Bx * HW * PTS * Cc);
    float*  part  = heat + (size_t)Bx * PTS * HW;   // 128 floats
    float*  statf = part + 128;                     // 128 floats

    dim3 blk(256);
    k_wconv  <<<dim3(384),              blk, 0, stream>>>(efw, w1, mw, wb, part);
    k_ef     <<<dim3(238, 4, Bx),       blk, 0, stream>>>(x, wbe, efb, efp);
    k_heat   <<<dim3(238, PTS, Bx),     blk, 0, stream>>>(efp, wb1, b1, w2, b2, heat);
    k_sample <<<dim3(480, PTS, Bx),     blk, 0, stream>>>(efp, heat, offs, outsb);
    k_merge  <<<dim3(238, 2, Bx),       blk, 0, stream>>>(outsb, wbm, mb, out, part);
    k_gnfinal<<<dim3(1), dim3(64),      0, stream>>>(part, statf);
    k_gnapply<<<dim3(Bx * Cc * HW / 4 / 256), blk, 0, stream>>>(out, statf, gg, gb);
}